// Round 1
// baseline (8501.932 us; speedup 1.0000x reference)
//
#include <hip/hip_runtime.h>
#include <hip/hip_bf16.h>

// Problem constants
#define B_    64
#define T_    512
#define I_    256
#define H_    1024
#define KTOT  1280          // I_ + H_
#define KSTEPS 40           // KTOT / 32
#define NWG   128           // recurrence workgroups (each owns NJ h-cols)
#define NJ    8             // h-columns per WG -> 32 gate columns
#define WPK_ELEMS (2 * KSTEPS * 64 * 8)   // 40960 bf16 per WG slice (80KB)

typedef __bf16 bf16x8 __attribute__((ext_vector_type(8)));
typedef float  f32x4  __attribute__((ext_vector_type(4)));

__device__ __forceinline__ unsigned short f2bf(float f) {
  unsigned u = __builtin_bit_cast(unsigned, f);
  u += 0x7FFFu + ((u >> 16) & 1u);       // round-to-nearest-even
  return (unsigned short)(u >> 16);
}
__device__ __forceinline__ float sigm(float x) { return 1.0f / (1.0f + __expf(-x)); }
__device__ __forceinline__ float tanh_fast(float x) {
  float ax = fabsf(x);
  float e  = __expf(-2.0f * ax);          // in (0,1], no overflow
  float t  = (1.0f - e) / (1.0f + e);
  return x < 0.0f ? -t : t;
}

// ---------------- K0: x [B,T,I] f32 -> xb [T,B,I] bf16 ----------------
__global__ void k_pack_x(const float* __restrict__ x, unsigned short* __restrict__ xb) {
  int idx = blockIdx.x * blockDim.x + threadIdx.x;   // over B*T*I/8 = 1,048,576
  int ic = idx & 31;             // I/8 = 32
  int t  = (idx >> 5) & 511;     // T = 512
  int b  = idx >> 14;            // B = 64
  const float* src = x + ((size_t)b * T_ + t) * I_ + ic * 8;
  float4 f0 = *(const float4*)src;
  float4 f1 = *(const float4*)(src + 4);
  unsigned short o[8] = {f2bf(f0.x), f2bf(f0.y), f2bf(f0.z), f2bf(f0.w),
                         f2bf(f1.x), f2bf(f1.y), f2bf(f1.z), f2bf(f1.w)};
  *(uint4*)(xb + ((size_t)t * B_ + b) * I_ + ic * 8) = *(uint4*)o;
}

// ---------------- K1a: pack W_ih|W_hh into per-WG B-fragment layout ----------------
// layout: [w][nt][kk][lane][e], value = W[gate*H + w*NJ + (n&7)][k] with
// n = lane&15 (n<8 -> gate nt*2, n>=8 -> gate nt*2+1), k = kk*32 + (lane>>4)*8 + e
__global__ void k_pack_w(const float* __restrict__ Wih, const float* __restrict__ Whh,
                         const float* __restrict__ bih, const float* __restrict__ bhh,
                         unsigned short* __restrict__ wpack, float* __restrict__ biasp) {
  int f = blockIdx.x * blockDim.x + threadIdx.x;     // 128*2*40*64 = 655,360
  int l  = f & 63;
  int q  = f >> 6;
  int kk = q % KSTEPS;
  int q2 = q / KSTEPS;
  int nt = q2 & 1;
  int w  = q2 >> 1;
  int n  = l & 15;
  int g  = nt * 2 + (n >> 3);
  int r  = g * H_ + w * NJ + (n & 7);
  int k0 = kk * 32 + (l >> 4) * 8;
  unsigned short o[8];
#pragma unroll
  for (int e = 0; e < 8; ++e) {
    int k = k0 + e;
    float v = (k < I_) ? Wih[(size_t)r * I_ + k] : Whh[(size_t)r * H_ + (k - I_)];
    o[e] = f2bf(v);
  }
  *(uint4*)(wpack + (size_t)f * 8) = *(uint4*)o;
  if (kk == 0 && (l >> 4) == 0) biasp[w * 32 + nt * 16 + n] = bih[r] + bhh[r];
}

// ---------------- K1b: pack W_fc [I,H] -> fragment layout [kk][nt][lane][e] ----------------
__global__ void k_pack_wfc(const float* __restrict__ Wfc, unsigned short* __restrict__ wfcp) {
  int f = blockIdx.x * blockDim.x + threadIdx.x;     // 32*16*64 = 32768
  int l  = f & 63;
  int nt = (f >> 6) & 15;
  int kk = f >> 10;
  int n  = nt * 16 + (l & 15);
  int k0 = kk * 32 + (l >> 4) * 8;
  unsigned short o[8];
#pragma unroll
  for (int e = 0; e < 8; ++e) o[e] = f2bf(Wfc[(size_t)n * H_ + k0 + e]);
  *(uint4*)(wfcp + (size_t)f * 8) = *(uint4*)o;
}

// ---------------- K1c: h0 -> bf16 hbuf[0]; zero barrier ----------------
__global__ void k_init_h(const float* __restrict__ h0, unsigned short* __restrict__ hbuf,
                         unsigned int* __restrict__ bar) {
  int idx = blockIdx.x * blockDim.x + threadIdx.x;   // B*H/8 = 8192
  const float* s = h0 + (size_t)idx * 8;
  unsigned short o[8];
#pragma unroll
  for (int e = 0; e < 8; ++e) o[e] = f2bf(s[e]);
  *(uint4*)(hbuf + (size_t)idx * 8) = *(uint4*)o;
  if (idx < 1024) bar[idx] = 0;
}

// ---------------- K2: persistent LSTM recurrence ----------------
// 128 WGs x 256 threads. WG w owns h-cols [w*8, w*8+8). W-slice resident in LDS.
// Per step: 4 waves x (M=16,N=32,K=1280) MFMA; c in registers; 1 global barrier.
__global__ void __launch_bounds__(256, 1) k_lstm(
    const unsigned short* __restrict__ xb, const unsigned short* __restrict__ wpack,
    const float* __restrict__ biasp, const float* __restrict__ c0,
    unsigned short* __restrict__ hbuf, unsigned short* __restrict__ hs,
    unsigned int* __restrict__ bar) {
  __shared__ unsigned short wlds[WPK_ELEMS];  // 80 KB
  const int w    = blockIdx.x;
  const int tid  = threadIdx.x;
  const int wave = tid >> 6, lane = tid & 63;

  { // one-time LDS fill of the W slice
    const unsigned short* wp = wpack + (size_t)w * WPK_ELEMS;
    for (int i = tid * 8; i < WPK_ELEMS; i += 256 * 8)
      *(uint4*)(wlds + i) = *(const uint4*)(wp + i);
  }

  const int mA   = wave * 16 + (lane & 15);    // A-fragment row = batch index
  const int kOff = (lane >> 4) * 8;            // A-fragment k offset within 32
  const int mD   = wave * 16 + (lane >> 4) * 4;// D-fragment row base
  const int j    = w * NJ + (lane & 7);        // owned h-column
  const bool own = (lane & 8) == 0;            // lanes n<8 own (i,g); n>=8 hold (f,o)

  const float bias0 = biasp[w * 32 + (lane & 15)];
  const float bias1 = biasp[w * 32 + 16 + (lane & 15)];
  float creg[4];
#pragma unroll
  for (int e = 0; e < 4; ++e) creg[e] = c0[(size_t)(mD + e) * H_ + j];

  __syncthreads();

  for (int t = 0; t < T_; ++t) {
    const unsigned short* hcur  = hbuf + (size_t)(t & 1) * (B_ * H_);
    unsigned short*       hnext = hbuf + (size_t)((t + 1) & 1) * (B_ * H_);
    f32x4 acc0 = {bias0, bias0, bias0, bias0};
    f32x4 acc1 = {bias1, bias1, bias1, bias1};
    const unsigned short* xrow = xb + ((size_t)t * B_ + mA) * I_ + kOff;
    const unsigned short* hrow = hcur + (size_t)mA * H_ + kOff;

#pragma unroll 4
    for (int kk = 0; kk < 8; ++kk) {           // K part from x_t
      bf16x8 a  = *(const bf16x8*)(xrow + kk * 32);
      bf16x8 b0 = *(const bf16x8*)(wlds + ((size_t)(kk) * 64 + lane) * 8);
      bf16x8 b1 = *(const bf16x8*)(wlds + ((size_t)(KSTEPS + kk) * 64 + lane) * 8);
      acc0 = __builtin_amdgcn_mfma_f32_16x16x32_bf16(a, b0, acc0, 0, 0, 0);
      acc1 = __builtin_amdgcn_mfma_f32_16x16x32_bf16(a, b1, acc1, 0, 0, 0);
    }
#pragma unroll 4
    for (int kk = 8; kk < KSTEPS; ++kk) {      // K part from h_{t-1}
      bf16x8 a  = *(const bf16x8*)(hrow + (kk - 8) * 32);
      bf16x8 b0 = *(const bf16x8*)(wlds + ((size_t)(kk) * 64 + lane) * 8);
      bf16x8 b1 = *(const bf16x8*)(wlds + ((size_t)(KSTEPS + kk) * 64 + lane) * 8);
      acc0 = __builtin_amdgcn_mfma_f32_16x16x32_bf16(a, b0, acc0, 0, 0, 0);
      acc1 = __builtin_amdgcn_mfma_f32_16x16x32_bf16(a, b1, acc1, 0, 0, 0);
    }

    // gates: acc0 = [i|f], acc1 = [g|o]; f/o live in lane^8
    unsigned short hbits[4];
#pragma unroll
    for (int e = 0; e < 4; ++e) {
      float ip  = acc0[e], gp = acc1[e];
      float fp_ = __shfl_xor(ip, 8);
      float op_ = __shfl_xor(gp, 8);
      float ig = sigm(ip), fg = sigm(fp_), gg = tanh_fast(gp), og = sigm(op_);
      float cn = fg * creg[e] + ig * gg;
      creg[e] = cn;
      hbits[e] = f2bf(og * tanh_fast(cn));
    }
    if (own) {
      size_t base = (size_t)mD * H_ + j;
      unsigned short* hsrow = hs + (size_t)t * (B_ * H_);
#pragma unroll
      for (int e = 0; e < 4; ++e) {
        hnext[base + (size_t)e * H_] = hbits[e];
        hsrow[base + (size_t)e * H_] = hbits[e];
      }
    }

    // device-wide step barrier (stores drained by syncthreads' vmcnt(0))
    __syncthreads();
    if (tid == 0) {
      __threadfence();  // release: write back this XCD's L2 to coherence point
      __hip_atomic_fetch_add(bar, 1u, __ATOMIC_RELAXED, __HIP_MEMORY_SCOPE_AGENT);
      const unsigned target = (unsigned)(t + 1) * NWG;
      int guard = 0;
      while (__hip_atomic_load(bar, __ATOMIC_RELAXED, __HIP_MEMORY_SCOPE_AGENT) < target) {
        __builtin_amdgcn_s_sleep(2);
        if (++guard > (1 << 24)) break;   // safety: never hard-hang the harness
      }
      __threadfence();  // acquire: invalidate stale L1/L2 before reading new h
    }
    __syncthreads();
  }
}

// ---------------- K3: out[t,b,:] = hs[t,b,:] @ W_fc^T + b_fc ----------------
__global__ void k_fc(const unsigned short* __restrict__ hs, const unsigned short* __restrict__ wfcp,
                     const float* __restrict__ bfc, float* __restrict__ out) {
  const int bm = blockIdx.x >> 2, bn = blockIdx.x & 3;
  const int tid = threadIdx.x, wave = tid >> 6, lane = tid & 63;
  const int r    = bm * 64 + wave * 16 + (lane & 15);
  const int kOff = (lane >> 4) * 8;
  const int nb   = bn * 4;   // first 16-wide n-tile index
  f32x4 acc[4];
#pragma unroll
  for (int nt = 0; nt < 4; ++nt) {
    float bv = bfc[(nb + nt) * 16 + (lane & 15)];
    acc[nt] = {bv, bv, bv, bv};
  }
  const unsigned short* arow = hs + (size_t)r * H_ + kOff;
#pragma unroll 2
  for (int kk = 0; kk < 32; ++kk) {
    bf16x8 a = *(const bf16x8*)(arow + kk * 32);
#pragma unroll
    for (int nt = 0; nt < 4; ++nt) {
      bf16x8 b = *(const bf16x8*)(wfcp + ((size_t)(kk * 16 + nb + nt) * 64 + lane) * 8);
      acc[nt] = __builtin_amdgcn_mfma_f32_16x16x32_bf16(a, b, acc[nt], 0, 0, 0);
    }
  }
  const int ro = bm * 64 + wave * 16 + (lane >> 4) * 4;
#pragma unroll
  for (int nt = 0; nt < 4; ++nt)
#pragma unroll
    for (int e = 0; e < 4; ++e)
      out[(size_t)(ro + e) * I_ + (nb + nt) * 16 + (lane & 15)] = acc[nt][e];
}

// ---------------- launcher ----------------
extern "C" void kernel_launch(void* const* d_in, const int* in_sizes, int n_in,
                              void* d_out, int out_size, void* d_ws, size_t ws_size,
                              hipStream_t stream) {
  const float* x   = (const float*)d_in[0];
  const float* h0  = (const float*)d_in[1];
  const float* c0  = (const float*)d_in[2];
  const float* Wih = (const float*)d_in[3];
  const float* Whh = (const float*)d_in[4];
  const float* bih = (const float*)d_in[5];
  const float* bhh = (const float*)d_in[6];
  const float* Wfc = (const float*)d_in[7];
  const float* bfc = (const float*)d_in[8];
  float* out = (float*)d_out;

  char* ws = (char*)d_ws;
  // ws layout (bytes): total ~95.2 MB
  unsigned short* xb    = (unsigned short*)(ws + 0);           // 16,777,216
  unsigned short* hsb   = (unsigned short*)(ws + 16777216);    // 67,108,864
  unsigned short* wpk   = (unsigned short*)(ws + 83886080);    // 10,485,760
  float*          biasp = (float*)        (ws + 94371840);     //     16,384
  unsigned short* wfcp  = (unsigned short*)(ws + 94388224);    //    524,288
  unsigned short* hbuf  = (unsigned short*)(ws + 94912512);    //    262,144
  unsigned int*   bar   = (unsigned int*)  (ws + 95174656);    //      4,096

  k_pack_x  <<<4096, 256, 0, stream>>>(x, xb);
  k_pack_w  <<<2560, 256, 0, stream>>>(Wih, Whh, bih, bhh, wpk, biasp);
  k_pack_wfc<<<128,  256, 0, stream>>>(Wfc, wfcp);
  k_init_h  <<<32,   256, 0, stream>>>(h0, hbuf, bar);
  k_lstm    <<<NWG,  256, 0, stream>>>(xb, wpk, biasp, c0, hbuf, hsb, bar);
  k_fc      <<<2048, 256, 0, stream>>>(hsb, wfcp, bfc, out);
}

// Round 2
// 6147.772 us; speedup vs baseline: 1.3829x; 1.3829x over previous
//
#include <hip/hip_runtime.h>
#include <hip/hip_bf16.h>

// Problem constants
#define B_    64
#define T_    512
#define I_    256
#define H_    1024
#define KTOT  1280          // I_ + H_
#define KSTEPS 40           // KTOT / 32
#define NWG   128           // recurrence workgroups (each owns NJ h-cols)
#define NJ    8             // h-columns per WG -> 32 gate columns
#define WPK_ELEMS (2 * KSTEPS * 64 * 8)   // 40960 bf16 per WG slice (80KB)

typedef __bf16 bf16x8 __attribute__((ext_vector_type(8)));
typedef float  f32x4  __attribute__((ext_vector_type(4)));
typedef unsigned long long u64x2 __attribute__((ext_vector_type(2)));

__device__ __forceinline__ unsigned short f2bf(float f) {
  unsigned u = __builtin_bit_cast(unsigned, f);
  u += 0x7FFFu + ((u >> 16) & 1u);       // round-to-nearest-even
  return (unsigned short)(u >> 16);
}
__device__ __forceinline__ float sigm(float x) { return 1.0f / (1.0f + __expf(-x)); }
__device__ __forceinline__ float tanh_fast(float x) {
  float ax = fabsf(x);
  float e  = __expf(-2.0f * ax);          // in (0,1], no overflow
  float t  = (1.0f - e) / (1.0f + e);
  return x < 0.0f ? -t : t;
}

// ---------------- K0: x [B,T,I] f32 -> xb [T,B,I] bf16 ----------------
__global__ void k_pack_x(const float* __restrict__ x, unsigned short* __restrict__ xb) {
  int idx = blockIdx.x * blockDim.x + threadIdx.x;   // over B*T*I/8 = 1,048,576
  int ic = idx & 31;             // I/8 = 32
  int t  = (idx >> 5) & 511;     // T = 512
  int b  = idx >> 14;            // B = 64
  const float* src = x + ((size_t)b * T_ + t) * I_ + ic * 8;
  float4 f0 = *(const float4*)src;
  float4 f1 = *(const float4*)(src + 4);
  unsigned short o[8] = {f2bf(f0.x), f2bf(f0.y), f2bf(f0.z), f2bf(f0.w),
                         f2bf(f1.x), f2bf(f1.y), f2bf(f1.z), f2bf(f1.w)};
  *(uint4*)(xb + ((size_t)t * B_ + b) * I_ + ic * 8) = *(uint4*)o;
}

// ---------------- K1a: pack W_ih|W_hh into per-WG B-fragment layout ----------------
__global__ void k_pack_w(const float* __restrict__ Wih, const float* __restrict__ Whh,
                         const float* __restrict__ bih, const float* __restrict__ bhh,
                         unsigned short* __restrict__ wpack, float* __restrict__ biasp) {
  int f = blockIdx.x * blockDim.x + threadIdx.x;     // 128*2*40*64 = 655,360
  int l  = f & 63;
  int q  = f >> 6;
  int kk = q % KSTEPS;
  int q2 = q / KSTEPS;
  int nt = q2 & 1;
  int w  = q2 >> 1;
  int n  = l & 15;
  int g  = nt * 2 + (n >> 3);
  int r  = g * H_ + w * NJ + (n & 7);
  int k0 = kk * 32 + (l >> 4) * 8;
  unsigned short o[8];
#pragma unroll
  for (int e = 0; e < 8; ++e) {
    int k = k0 + e;
    float v = (k < I_) ? Wih[(size_t)r * I_ + k] : Whh[(size_t)r * H_ + (k - I_)];
    o[e] = f2bf(v);
  }
  *(uint4*)(wpack + (size_t)f * 8) = *(uint4*)o;
  if (kk == 0 && (l >> 4) == 0) biasp[w * 32 + nt * 16 + n] = bih[r] + bhh[r];
}

// ---------------- K1b: pack W_fc [I,H] -> fragment layout [kk][nt][lane][e] ----------------
__global__ void k_pack_wfc(const float* __restrict__ Wfc, unsigned short* __restrict__ wfcp) {
  int f = blockIdx.x * blockDim.x + threadIdx.x;     // 32*16*64 = 32768
  int l  = f & 63;
  int nt = (f >> 6) & 15;
  int kk = f >> 10;
  int n  = nt * 16 + (l & 15);
  int k0 = kk * 32 + (l >> 4) * 8;
  unsigned short o[8];
#pragma unroll
  for (int e = 0; e < 8; ++e) o[e] = f2bf(Wfc[(size_t)n * H_ + k0 + e]);
  *(uint4*)(wfcp + (size_t)f * 8) = *(uint4*)o;
}

// ---------------- K1c: h0 -> bf16 hbuf; zero flags ----------------
__global__ void k_init_h(const float* __restrict__ h0, unsigned short* __restrict__ hbuf,
                         unsigned int* __restrict__ flags) {
  int idx = blockIdx.x * blockDim.x + threadIdx.x;   // B*H/8 = 8192
  const float* s = h0 + (size_t)idx * 8;
  unsigned short o[8];
#pragma unroll
  for (int e = 0; e < 8; ++e) o[e] = f2bf(s[e]);
  *(uint4*)(hbuf + (size_t)idx * 8) = *(uint4*)o;
  if (idx < 1024) flags[idx] = 0;
}

// ---------------- K2: persistent LSTM recurrence ----------------
// 128 WGs x 256 threads. WG w owns h-cols [w*8, w*8+8). W-slice resident in LDS.
// h exchange: write-through (agent-scope atomic) stores into hs[t]; per-WG flag
// array barrier (parallel stores + coalesced poll). No threadfence, no L2 inval.
__global__ void __launch_bounds__(256, 1) k_lstm(
    const unsigned short* __restrict__ xb, const unsigned short* __restrict__ wpack,
    const float* __restrict__ biasp, const float* __restrict__ c0,
    const unsigned short* __restrict__ hbuf, unsigned short* __restrict__ hs,
    unsigned int* __restrict__ flags) {
  __shared__ unsigned short wlds[WPK_ELEMS];  // 80 KB
  const int w    = blockIdx.x;
  const int tid  = threadIdx.x;
  const int wave = tid >> 6, lane = tid & 63;

  { // one-time LDS fill of the W slice
    const unsigned short* wp = wpack + (size_t)w * WPK_ELEMS;
    for (int i = tid * 8; i < WPK_ELEMS; i += 256 * 8)
      *(uint4*)(wlds + i) = *(const uint4*)(wp + i);
  }

  const int mA   = wave * 16 + (lane & 15);    // A-fragment row = batch index
  const int kOff = (lane >> 4) * 8;            // A-fragment k offset within 32
  const int mD   = wave * 16 + (lane >> 4) * 4;// D-fragment row base
  const int jst  = w * NJ + (lane & 7);        // owned h-column (store col for even pairs)

  const float bias0 = biasp[w * 32 + (lane & 15)];
  const float bias1 = biasp[w * 32 + 16 + (lane & 15)];
  float creg[4];
#pragma unroll
  for (int e = 0; e < 4; ++e) creg[e] = c0[(size_t)(mD + e) * H_ + jst];

  __syncthreads();

  f32x4 xacc0, xacc1;
  // x-part of gates for step t (bias folded in); overlaps barrier/store-drain
  auto computeX = [&](int t) {
    xacc0 = f32x4{bias0, bias0, bias0, bias0};
    xacc1 = f32x4{bias1, bias1, bias1, bias1};
    const unsigned short* xrow = xb + ((size_t)t * B_ + mA) * I_ + kOff;
#pragma unroll
    for (int kk = 0; kk < 8; ++kk) {
      bf16x8 a  = *(const bf16x8*)(xrow + kk * 32);
      bf16x8 b0 = *(const bf16x8*)(wlds + ((size_t)(kk) * 64 + lane) * 8);
      bf16x8 b1 = *(const bf16x8*)(wlds + ((size_t)(KSTEPS + kk) * 64 + lane) * 8);
      xacc0 = __builtin_amdgcn_mfma_f32_16x16x32_bf16(a, b0, xacc0, 0, 0, 0);
      xacc1 = __builtin_amdgcn_mfma_f32_16x16x32_bf16(a, b1, xacc1, 0, 0, 0);
    }
  };
  computeX(0);

  for (int t = 0; t < T_; ++t) {
    // ---- wait for h_{t-1} (all WGs posted flag >= t) ----
    if (wave == 0 && t > 0) {
      const unsigned target = (unsigned)t;
      const unsigned long long* fp = (const unsigned long long*)flags + lane; // flags[2L..2L+1]
      int guard = 0;
      for (;;) {
        unsigned long long v = __hip_atomic_load(fp, __ATOMIC_RELAXED, __HIP_MEMORY_SCOPE_AGENT);
        unsigned lo = (unsigned)v, hi = (unsigned)(v >> 32);
        if (__all(lo >= target && hi >= target)) break;
        if (++guard > (1 << 20)) break;   // safety: never hard-hang the harness
      }
    }
    __syncthreads();

    f32x4 acc0 = xacc0, acc1 = xacc1;
    const unsigned short* hprev = (t == 0) ? hbuf : hs + (size_t)(t - 1) * (B_ * H_);
    const unsigned long long* hrow =
        (const unsigned long long*)(hprev + (size_t)mA * H_ + kOff);
#pragma unroll
    for (int kk = 0; kk < 32; ++kk) {
      // coherence-safe read of other XCDs' write-through data (bypasses stale L2)
      u64x2 hv;
      hv.x = __hip_atomic_load(hrow + kk * 8, __ATOMIC_RELAXED, __HIP_MEMORY_SCOPE_AGENT);
      hv.y = __hip_atomic_load(hrow + kk * 8 + 1, __ATOMIC_RELAXED, __HIP_MEMORY_SCOPE_AGENT);
      bf16x8 a  = __builtin_bit_cast(bf16x8, hv);
      bf16x8 b0 = *(const bf16x8*)(wlds + ((size_t)(kk + 8) * 64 + lane) * 8);
      bf16x8 b1 = *(const bf16x8*)(wlds + ((size_t)(KSTEPS + kk + 8) * 64 + lane) * 8);
      acc0 = __builtin_amdgcn_mfma_f32_16x16x32_bf16(a, b0, acc0, 0, 0, 0);
      acc1 = __builtin_amdgcn_mfma_f32_16x16x32_bf16(a, b1, acc1, 0, 0, 0);
    }

    // gates: acc0 = [i|f], acc1 = [g|o]; f/o live in lane^8
    unsigned short hbits[4];
#pragma unroll
    for (int e = 0; e < 4; ++e) {
      float ip  = acc0[e], gp = acc1[e];
      float fp_ = __shfl_xor(ip, 8);
      float op_ = __shfl_xor(gp, 8);
      float ig = sigm(ip), fg = sigm(fp_), gg = tanh_fast(gp), og = sigm(op_);
      float cn = fg * creg[e] + ig * gg;
      creg[e] = cn;
      hbits[e] = f2bf(og * tanh_fast(cn));
    }

    // store h_t into hs[t]: pair adjacent columns into one dword, write-through
    unsigned short* hsrow = hs + (size_t)t * (B_ * H_);
#pragma unroll
    for (int e = 0; e < 4; ++e) {
      unsigned vpair = (unsigned)hbits[e] | ((unsigned)__shfl_xor((int)hbits[e], 1) << 16);
      if ((lane & 9) == 0) {   // even lanes among owners (lane&8==0)
        unsigned* dst = (unsigned*)(hsrow + (size_t)(mD + e) * H_ + jst);
        __hip_atomic_store(dst, vpair, __ATOMIC_RELAXED, __HIP_MEMORY_SCOPE_AGENT);
      }
    }

    // overlap next step's x-part with store drain
    if (t + 1 < T_) computeX(t + 1);

    __syncthreads();   // implicit vmcnt(0): all waves' write-through stores done
    if (tid == 0)
      __hip_atomic_store(flags + w, (unsigned)(t + 1), __ATOMIC_RELAXED, __HIP_MEMORY_SCOPE_AGENT);
  }
}

// ---------------- K3: out[t,b,:] = hs[t,b,:] @ W_fc^T + b_fc ----------------
__global__ void k_fc(const unsigned short* __restrict__ hs, const unsigned short* __restrict__ wfcp,
                     const float* __restrict__ bfc, float* __restrict__ out) {
  const int bm = blockIdx.x >> 2, bn = blockIdx.x & 3;
  const int tid = threadIdx.x, wave = tid >> 6, lane = tid & 63;
  const int r    = bm * 64 + wave * 16 + (lane & 15);
  const int kOff = (lane >> 4) * 8;
  const int nb   = bn * 4;   // first 16-wide n-tile index
  f32x4 acc[4];
#pragma unroll
  for (int nt = 0; nt < 4; ++nt) {
    float bv = bfc[(nb + nt) * 16 + (lane & 15)];
    acc[nt] = {bv, bv, bv, bv};
  }
  const unsigned short* arow = hs + (size_t)r * H_ + kOff;
#pragma unroll 2
  for (int kk = 0; kk < 32; ++kk) {
    bf16x8 a = *(const bf16x8*)(arow + kk * 32);
#pragma unroll
    for (int nt = 0; nt < 4; ++nt) {
      bf16x8 b = *(const bf16x8*)(wfcp + ((size_t)(kk * 16 + nb + nt) * 64 + lane) * 8);
      acc[nt] = __builtin_amdgcn_mfma_f32_16x16x32_bf16(a, b, acc[nt], 0, 0, 0);
    }
  }
  const int ro = bm * 64 + wave * 16 + (lane >> 4) * 4;
#pragma unroll
  for (int nt = 0; nt < 4; ++nt)
#pragma unroll
    for (int e = 0; e < 4; ++e)
      out[(size_t)(ro + e) * I_ + (nb + nt) * 16 + (lane & 15)] = acc[nt][e];
}

// ---------------- launcher ----------------
extern "C" void kernel_launch(void* const* d_in, const int* in_sizes, int n_in,
                              void* d_out, int out_size, void* d_ws, size_t ws_size,
                              hipStream_t stream) {
  const float* x   = (const float*)d_in[0];
  const float* h0  = (const float*)d_in[1];
  const float* c0  = (const float*)d_in[2];
  const float* Wih = (const float*)d_in[3];
  const float* Whh = (const float*)d_in[4];
  const float* bih = (const float*)d_in[5];
  const float* bhh = (const float*)d_in[6];
  const float* Wfc = (const float*)d_in[7];
  const float* bfc = (const float*)d_in[8];
  float* out = (float*)d_out;

  char* ws = (char*)d_ws;
  // ws layout (bytes): total ~95.2 MB
  unsigned short* xb    = (unsigned short*)(ws + 0);           // 16,777,216
  unsigned short* hsb   = (unsigned short*)(ws + 16777216);    // 67,108,864
  unsigned short* wpk   = (unsigned short*)(ws + 83886080);    // 10,485,760
  float*          biasp = (float*)        (ws + 94371840);     //     16,384
  unsigned short* wfcp  = (unsigned short*)(ws + 94388224);    //    524,288
  unsigned short* hbuf  = (unsigned short*)(ws + 94912512);    //    262,144
  unsigned int*   flg   = (unsigned int*)  (ws + 95174656);    //      4,096

  k_pack_x  <<<4096, 256, 0, stream>>>(x, xb);
  k_pack_w  <<<2560, 256, 0, stream>>>(Wih, Whh, bih, bhh, wpk, biasp);
  k_pack_wfc<<<128,  256, 0, stream>>>(Wfc, wfcp);
  k_init_h  <<<32,   256, 0, stream>>>(h0, hbuf, flg);
  k_lstm    <<<NWG,  256, 0, stream>>>(xb, wpk, biasp, c0, hbuf, hsb, flg);
  k_fc      <<<2048, 256, 0, stream>>>(hsb, wfcp, bfc, out);
}

// Round 3
// 4870.781 us; speedup vs baseline: 1.7455x; 1.2622x over previous
//
#include <hip/hip_runtime.h>
#include <hip/hip_bf16.h>

// Problem constants
#define B_    64
#define T_    512
#define I_    256
#define H_    1024
#define KTOT  1280          // I_ + H_
#define KSTEPS 40           // KTOT / 32
#define NWG   128           // recurrence workgroups (each owns NJ h-cols)
#define NJ    8             // h-columns per WG -> 32 gate columns
#define WPK_ELEMS (2 * KSTEPS * 64 * 8)   // 40960 bf16 per WG slice (80KB)

typedef __bf16 bf16x8 __attribute__((ext_vector_type(8)));
typedef float  f32x4  __attribute__((ext_vector_type(4)));

__device__ __forceinline__ unsigned short f2bf(float f) {
  unsigned u = __builtin_bit_cast(unsigned, f);
  u += 0x7FFFu + ((u >> 16) & 1u);       // round-to-nearest-even
  return (unsigned short)(u >> 16);
}
__device__ __forceinline__ float sigm(float x) { return 1.0f / (1.0f + __expf(-x)); }
__device__ __forceinline__ float tanh_fast(float x) {
  float ax = fabsf(x);
  float e  = __expf(-2.0f * ax);          // in (0,1], no overflow
  float t  = (1.0f - e) / (1.0f + e);
  return x < 0.0f ? -t : t;
}

// ---------------- K0: x [B,T,I] f32 -> xb [T,B,I] bf16 ----------------
__global__ void k_pack_x(const float* __restrict__ x, unsigned short* __restrict__ xb) {
  int idx = blockIdx.x * blockDim.x + threadIdx.x;   // over B*T*I/8 = 1,048,576
  int ic = idx & 31;             // I/8 = 32
  int t  = (idx >> 5) & 511;     // T = 512
  int b  = idx >> 14;            // B = 64
  const float* src = x + ((size_t)b * T_ + t) * I_ + ic * 8;
  float4 f0 = *(const float4*)src;
  float4 f1 = *(const float4*)(src + 4);
  unsigned short o[8] = {f2bf(f0.x), f2bf(f0.y), f2bf(f0.z), f2bf(f0.w),
                         f2bf(f1.x), f2bf(f1.y), f2bf(f1.z), f2bf(f1.w)};
  *(uint4*)(xb + ((size_t)t * B_ + b) * I_ + ic * 8) = *(uint4*)o;
}

// ---------------- K1a: pack W_ih|W_hh into per-WG B-fragment layout ----------------
__global__ void k_pack_w(const float* __restrict__ Wih, const float* __restrict__ Whh,
                         const float* __restrict__ bih, const float* __restrict__ bhh,
                         unsigned short* __restrict__ wpack, float* __restrict__ biasp) {
  int f = blockIdx.x * blockDim.x + threadIdx.x;     // 128*2*40*64 = 655,360
  int l  = f & 63;
  int q  = f >> 6;
  int kk = q % KSTEPS;
  int q2 = q / KSTEPS;
  int nt = q2 & 1;
  int w  = q2 >> 1;
  int n  = l & 15;
  int g  = nt * 2 + (n >> 3);
  int r  = g * H_ + w * NJ + (n & 7);
  int k0 = kk * 32 + (l >> 4) * 8;
  unsigned short o[8];
#pragma unroll
  for (int e = 0; e < 8; ++e) {
    int k = k0 + e;
    float v = (k < I_) ? Wih[(size_t)r * I_ + k] : Whh[(size_t)r * H_ + (k - I_)];
    o[e] = f2bf(v);
  }
  *(uint4*)(wpack + (size_t)f * 8) = *(uint4*)o;
  if (kk == 0 && (l >> 4) == 0) biasp[w * 32 + nt * 16 + n] = bih[r] + bhh[r];
}

// ---------------- K1b: pack W_fc [I,H] -> fragment layout [kk][nt][lane][e] ----------------
__global__ void k_pack_wfc(const float* __restrict__ Wfc, unsigned short* __restrict__ wfcp) {
  int f = blockIdx.x * blockDim.x + threadIdx.x;     // 32*16*64 = 32768
  int l  = f & 63;
  int nt = (f >> 6) & 15;
  int kk = f >> 10;
  int n  = nt * 16 + (l & 15);
  int k0 = kk * 32 + (l >> 4) * 8;
  unsigned short o[8];
#pragma unroll
  for (int e = 0; e < 8; ++e) o[e] = f2bf(Wfc[(size_t)n * H_ + k0 + e]);
  *(uint4*)(wfcp + (size_t)f * 8) = *(uint4*)o;
}

// ---------------- K1c: h0 -> bf16 hbuf; zero flags ----------------
__global__ void k_init_h(const float* __restrict__ h0, unsigned short* __restrict__ hbuf,
                         unsigned int* __restrict__ flags) {
  int idx = blockIdx.x * blockDim.x + threadIdx.x;   // B*H/8 = 8192
  const float* s = h0 + (size_t)idx * 8;
  unsigned short o[8];
#pragma unroll
  for (int e = 0; e < 8; ++e) o[e] = f2bf(s[e]);
  *(uint4*)(hbuf + (size_t)idx * 8) = *(uint4*)o;
  if (idx < 1024) flags[idx] = 0;
}

// ---------------- K2: persistent LSTM recurrence ----------------
// 128 WGs x 256 threads. WG w owns h-cols [w*8, w*8+8). W-slice resident in LDS.
// Producer side: write-through (sc1) stores of h into hs[t] + sc1 flag post.
// Consumer side: sc1 poll of flags, then PLAIN cached b128 loads of h.
// Safety: each hs[t] line is written once (write-through) and first read on any
// XCD only after that XCD saw flags>=t+1 (data at MALL) -> L1/L2 fills can
// never capture stale data; kernel-start acquire invalidated pre-kernel lines.
__global__ void __launch_bounds__(256, 1) k_lstm(
    const unsigned short* __restrict__ xb, const unsigned short* __restrict__ wpack,
    const float* __restrict__ biasp, const float* __restrict__ c0,
    const unsigned short* __restrict__ hbuf, unsigned short* __restrict__ hs,
    unsigned int* __restrict__ flags) {
  __shared__ unsigned short wlds[WPK_ELEMS];  // 80 KB
  const int w    = blockIdx.x;
  const int tid  = threadIdx.x;
  const int wave = tid >> 6, lane = tid & 63;

  { // one-time LDS fill of the W slice
    const unsigned short* wp = wpack + (size_t)w * WPK_ELEMS;
    for (int i = tid * 8; i < WPK_ELEMS; i += 256 * 8)
      *(uint4*)(wlds + i) = *(const uint4*)(wp + i);
  }

  const int mA   = wave * 16 + (lane & 15);    // A-fragment row = batch index
  const int kOff = (lane >> 4) * 8;            // A-fragment k offset within 32
  const int mD   = wave * 16 + (lane >> 4) * 4;// D-fragment row base
  const int jst  = w * NJ + (lane & 7);        // owned h-column

  const float bias0 = biasp[w * 32 + (lane & 15)];
  const float bias1 = biasp[w * 32 + 16 + (lane & 15)];
  float creg[4];
#pragma unroll
  for (int e = 0; e < 4; ++e) creg[e] = c0[(size_t)(mD + e) * H_ + jst];

  __syncthreads();

  f32x4 xacc0, xacc1;
  // x-part of gates for step t (bias folded in); overlaps barrier/store-drain
  auto computeX = [&](int t) {
    xacc0 = f32x4{bias0, bias0, bias0, bias0};
    xacc1 = f32x4{bias1, bias1, bias1, bias1};
    const unsigned short* xrow = xb + ((size_t)t * B_ + mA) * I_ + kOff;
#pragma unroll
    for (int kk = 0; kk < 8; ++kk) {
      bf16x8 a  = *(const bf16x8*)(xrow + kk * 32);
      bf16x8 b0 = *(const bf16x8*)(wlds + ((size_t)(kk) * 64 + lane) * 8);
      bf16x8 b1 = *(const bf16x8*)(wlds + ((size_t)(KSTEPS + kk) * 64 + lane) * 8);
      xacc0 = __builtin_amdgcn_mfma_f32_16x16x32_bf16(a, b0, xacc0, 0, 0, 0);
      xacc1 = __builtin_amdgcn_mfma_f32_16x16x32_bf16(a, b1, xacc1, 0, 0, 0);
    }
  };
  computeX(0);

  for (int t = 0; t < T_; ++t) {
    // ---- wait for h_{t-1} (all WGs posted flag >= t) ----
    if (wave == 0 && t > 0) {
      const unsigned target = (unsigned)t;
      const unsigned long long* fp = (const unsigned long long*)flags + lane; // flags[2L..2L+1]
      int guard = 0;
      for (;;) {
        unsigned long long v = __hip_atomic_load(fp, __ATOMIC_RELAXED, __HIP_MEMORY_SCOPE_AGENT);
        unsigned lo = (unsigned)v, hi = (unsigned)(v >> 32);
        if (__all(lo >= target && hi >= target)) break;
        if (++guard > (1 << 20)) break;   // safety: never hard-hang the harness
      }
    }
    __syncthreads();   // orders poll before h loads for all waves (compiler + HW)

    f32x4 acc0 = xacc0, acc1 = xacc1;
    const unsigned short* hprev = (t == 0) ? hbuf : hs + (size_t)(t - 1) * (B_ * H_);
    const unsigned short* hrow = hprev + (size_t)mA * H_ + kOff;
#pragma unroll
    for (int kk = 0; kk < 32; ++kk) {
      bf16x8 a  = *(const bf16x8*)(hrow + kk * 32);   // plain cached b128 load
      bf16x8 b0 = *(const bf16x8*)(wlds + ((size_t)(kk + 8) * 64 + lane) * 8);
      bf16x8 b1 = *(const bf16x8*)(wlds + ((size_t)(KSTEPS + kk + 8) * 64 + lane) * 8);
      acc0 = __builtin_amdgcn_mfma_f32_16x16x32_bf16(a, b0, acc0, 0, 0, 0);
      acc1 = __builtin_amdgcn_mfma_f32_16x16x32_bf16(a, b1, acc1, 0, 0, 0);
    }

    // gates: acc0 = [i|f], acc1 = [g|o]; f/o live in lane^8
    unsigned short hbits[4];
#pragma unroll
    for (int e = 0; e < 4; ++e) {
      float ip  = acc0[e], gp = acc1[e];
      float fp_ = __shfl_xor(ip, 8);
      float op_ = __shfl_xor(gp, 8);
      float ig = sigm(ip), fg = sigm(fp_), gg = tanh_fast(gp), og = sigm(op_);
      float cn = fg * creg[e] + ig * gg;
      creg[e] = cn;
      hbits[e] = f2bf(og * tanh_fast(cn));
    }

    // store h_t into hs[t]: pair adjacent columns into one dword, write-through
    unsigned short* hsrow = hs + (size_t)t * (B_ * H_);
#pragma unroll
    for (int e = 0; e < 4; ++e) {
      unsigned vpair = (unsigned)hbits[e] | ((unsigned)__shfl_xor((int)hbits[e], 1) << 16);
      if ((lane & 9) == 0) {   // even lanes among owners (lane&8==0)
        unsigned* dst = (unsigned*)(hsrow + (size_t)(mD + e) * H_ + jst);
        __hip_atomic_store(dst, vpair, __ATOMIC_RELAXED, __HIP_MEMORY_SCOPE_AGENT);
      }
    }

    // overlap next step's x-part with store drain
    if (t + 1 < T_) computeX(t + 1);

    __syncthreads();   // implicit vmcnt(0): all waves' write-through stores done
    if (tid == 0)
      __hip_atomic_store(flags + w, (unsigned)(t + 1), __ATOMIC_RELAXED, __HIP_MEMORY_SCOPE_AGENT);
  }
}

// ---------------- K3: out[t,b,:] = hs[t,b,:] @ W_fc^T + b_fc ----------------
__global__ void k_fc(const unsigned short* __restrict__ hs, const unsigned short* __restrict__ wfcp,
                     const float* __restrict__ bfc, float* __restrict__ out) {
  const int bm = blockIdx.x >> 2, bn = blockIdx.x & 3;
  const int tid = threadIdx.x, wave = tid >> 6, lane = tid & 63;
  const int r    = bm * 64 + wave * 16 + (lane & 15);
  const int kOff = (lane >> 4) * 8;
  const int nb   = bn * 4;   // first 16-wide n-tile index
  f32x4 acc[4];
#pragma unroll
  for (int nt = 0; nt < 4; ++nt) {
    float bv = bfc[(nb + nt) * 16 + (lane & 15)];
    acc[nt] = {bv, bv, bv, bv};
  }
  const unsigned short* arow = hs + (size_t)r * H_ + kOff;
#pragma unroll 2
  for (int kk = 0; kk < 32; ++kk) {
    bf16x8 a = *(const bf16x8*)(arow + kk * 32);
#pragma unroll
    for (int nt = 0; nt < 4; ++nt) {
      bf16x8 b = *(const bf16x8*)(wfcp + ((size_t)(kk * 16 + nb + nt) * 64 + lane) * 8);
      acc[nt] = __builtin_amdgcn_mfma_f32_16x16x32_bf16(a, b, acc[nt], 0, 0, 0);
    }
  }
  const int ro = bm * 64 + wave * 16 + (lane >> 4) * 4;
#pragma unroll
  for (int nt = 0; nt < 4; ++nt)
#pragma unroll
    for (int e = 0; e < 4; ++e)
      out[(size_t)(ro + e) * I_ + (nb + nt) * 16 + (lane & 15)] = acc[nt][e];
}

// ---------------- launcher ----------------
extern "C" void kernel_launch(void* const* d_in, const int* in_sizes, int n_in,
                              void* d_out, int out_size, void* d_ws, size_t ws_size,
                              hipStream_t stream) {
  const float* x   = (const float*)d_in[0];
  const float* h0  = (const float*)d_in[1];
  const float* c0  = (const float*)d_in[2];
  const float* Wih = (const float*)d_in[3];
  const float* Whh = (const float*)d_in[4];
  const float* bih = (const float*)d_in[5];
  const float* bhh = (const float*)d_in[6];
  const float* Wfc = (const float*)d_in[7];
  const float* bfc = (const float*)d_in[8];
  float* out = (float*)d_out;

  char* ws = (char*)d_ws;
  // ws layout (bytes): total ~95.2 MB
  unsigned short* xb    = (unsigned short*)(ws + 0);           // 16,777,216
  unsigned short* hsb   = (unsigned short*)(ws + 16777216);    // 67,108,864
  unsigned short* wpk   = (unsigned short*)(ws + 83886080);    // 10,485,760
  float*          biasp = (float*)        (ws + 94371840);     //     16,384
  unsigned short* wfcp  = (unsigned short*)(ws + 94388224);    //    524,288
  unsigned short* hbuf  = (unsigned short*)(ws + 94912512);    //    262,144
  unsigned int*   flg   = (unsigned int*)  (ws + 95174656);    //      4,096

  k_pack_x  <<<4096, 256, 0, stream>>>(x, xb);
  k_pack_w  <<<2560, 256, 0, stream>>>(Wih, Whh, bih, bhh, wpk, biasp);
  k_pack_wfc<<<128,  256, 0, stream>>>(Wfc, wfcp);
  k_init_h  <<<32,   256, 0, stream>>>(h0, hbuf, flg);
  k_lstm    <<<NWG,  256, 0, stream>>>(xb, wpk, biasp, c0, hbuf, hsb, flg);
  k_fc      <<<2048, 256, 0, stream>>>(hsb, wfcp, bfc, out);
}

// Round 4
// 3962.576 us; speedup vs baseline: 2.1456x; 1.2292x over previous
//
#include <hip/hip_runtime.h>
#include <hip/hip_bf16.h>

// Problem constants
#define B_    64
#define T_    512
#define I_    256
#define H_    1024
#define KTOT  1280          // I_ + H_
#define KSTEPS 40           // KTOT / 32
#define NWG   128           // recurrence workgroups (each owns NJ h-cols)
#define NJ    8             // h-columns per WG -> 32 gate columns
#define WPK_ELEMS (2 * KSTEPS * 64 * 8)   // 40960 bf16 per WG slice (80KB)

typedef __bf16 bf16x8 __attribute__((ext_vector_type(8)));
typedef float  f32x4  __attribute__((ext_vector_type(4)));

__device__ __forceinline__ unsigned short f2bf(float f) {
  unsigned u = __builtin_bit_cast(unsigned, f);
  u += 0x7FFFu + ((u >> 16) & 1u);       // round-to-nearest-even
  return (unsigned short)(u >> 16);
}
__device__ __forceinline__ float sigm(float x) { return 1.0f / (1.0f + __expf(-x)); }
__device__ __forceinline__ float tanh_fast(float x) {
  float ax = fabsf(x);
  float e  = __expf(-2.0f * ax);          // in (0,1], no overflow
  float t  = (1.0f - e) / (1.0f + e);
  return x < 0.0f ? -t : t;
}

// ---------------- K0: x [B,T,I] f32 -> xb [T,B,I] bf16 ----------------
__global__ void k_pack_x(const float* __restrict__ x, unsigned short* __restrict__ xb) {
  int idx = blockIdx.x * blockDim.x + threadIdx.x;   // over B*T*I/8 = 1,048,576
  int ic = idx & 31;             // I/8 = 32
  int t  = (idx >> 5) & 511;     // T = 512
  int b  = idx >> 14;            // B = 64
  const float* src = x + ((size_t)b * T_ + t) * I_ + ic * 8;
  float4 f0 = *(const float4*)src;
  float4 f1 = *(const float4*)(src + 4);
  unsigned short o[8] = {f2bf(f0.x), f2bf(f0.y), f2bf(f0.z), f2bf(f0.w),
                         f2bf(f1.x), f2bf(f1.y), f2bf(f1.z), f2bf(f1.w)};
  *(uint4*)(xb + ((size_t)t * B_ + b) * I_ + ic * 8) = *(uint4*)o;
}

// ---------------- K1a: pack W_ih|W_hh into per-WG B-fragment layout ----------------
__global__ void k_pack_w(const float* __restrict__ Wih, const float* __restrict__ Whh,
                         const float* __restrict__ bih, const float* __restrict__ bhh,
                         unsigned short* __restrict__ wpack, float* __restrict__ biasp) {
  int f = blockIdx.x * blockDim.x + threadIdx.x;     // 128*2*40*64 = 655,360
  int l  = f & 63;
  int q  = f >> 6;
  int kk = q % KSTEPS;
  int q2 = q / KSTEPS;
  int nt = q2 & 1;
  int w  = q2 >> 1;
  int n  = l & 15;
  int g  = nt * 2 + (n >> 3);
  int r  = g * H_ + w * NJ + (n & 7);
  int k0 = kk * 32 + (l >> 4) * 8;
  unsigned short o[8];
#pragma unroll
  for (int e = 0; e < 8; ++e) {
    int k = k0 + e;
    float v = (k < I_) ? Wih[(size_t)r * I_ + k] : Whh[(size_t)r * H_ + (k - I_)];
    o[e] = f2bf(v);
  }
  *(uint4*)(wpack + (size_t)f * 8) = *(uint4*)o;
  if (kk == 0 && (l >> 4) == 0) biasp[w * 32 + nt * 16 + n] = bih[r] + bhh[r];
}

// ---------------- K1b: pack W_fc [I,H] -> fragment layout [kk][nt][lane][e] ----------------
__global__ void k_pack_wfc(const float* __restrict__ Wfc, unsigned short* __restrict__ wfcp) {
  int f = blockIdx.x * blockDim.x + threadIdx.x;     // 32*16*64 = 32768
  int l  = f & 63;
  int nt = (f >> 6) & 15;
  int kk = f >> 10;
  int n  = nt * 16 + (l & 15);
  int k0 = kk * 32 + (l >> 4) * 8;
  unsigned short o[8];
#pragma unroll
  for (int e = 0; e < 8; ++e) o[e] = f2bf(Wfc[(size_t)n * H_ + k0 + e]);
  *(uint4*)(wfcp + (size_t)f * 8) = *(uint4*)o;
}

// ---------------- K1c: h0 -> bf16 hbuf; zero flags ----------------
__global__ void k_init_h(const float* __restrict__ h0, unsigned short* __restrict__ hbuf,
                         unsigned int* __restrict__ flags) {
  int idx = blockIdx.x * blockDim.x + threadIdx.x;   // B*H/8 = 8192
  const float* s = h0 + (size_t)idx * 8;
  unsigned short o[8];
#pragma unroll
  for (int e = 0; e < 8; ++e) o[e] = f2bf(s[e]);
  *(uint4*)(hbuf + (size_t)idx * 8) = *(uint4*)o;
  if (idx < 1024) flags[idx] = 0;
}

// ---------------- K2: persistent LSTM recurrence ----------------
// 128 WGs x 256 threads (4 waves). WG w owns h-cols [w*8, w*8+8). W in LDS.
// Waves run DECOUPLED in the loop (no __syncthreads): per-wave flags (512),
// each wave posts after its own vmcnt(0) drain and polls all 512 itself.
// h exchange: sc1 write-through stores into hs[t]; readers use plain cached
// b128 loads, prefetched 32-deep into registers before the MFMA chain.
__global__ void __launch_bounds__(256, 1) k_lstm(
    const unsigned short* __restrict__ xb, const unsigned short* __restrict__ wpack,
    const float* __restrict__ biasp, const float* __restrict__ c0,
    const unsigned short* __restrict__ hbuf, unsigned short* __restrict__ hs,
    unsigned int* __restrict__ flags) {
  __shared__ unsigned short wlds[WPK_ELEMS];  // 80 KB
  const int w    = blockIdx.x;
  const int tid  = threadIdx.x;
  const int wave = tid >> 6, lane = tid & 63;

  { // one-time LDS fill of the W slice
    const unsigned short* wp = wpack + (size_t)w * WPK_ELEMS;
    for (int i = tid * 8; i < WPK_ELEMS; i += 256 * 8)
      *(uint4*)(wlds + i) = *(const uint4*)(wp + i);
  }

  const int mA   = wave * 16 + (lane & 15);    // A-fragment row = batch index
  const int kOff = (lane >> 4) * 8;            // A-fragment k offset within 32
  const int mD   = wave * 16 + (lane >> 4) * 4;// D-fragment row base
  const int jst  = w * NJ + (lane & 7);        // owned h-column

  const float bias0 = biasp[w * 32 + (lane & 15)];
  const float bias1 = biasp[w * 32 + 16 + (lane & 15)];
  float creg[4];
#pragma unroll
  for (int e = 0; e < 4; ++e) creg[e] = c0[(size_t)(mD + e) * H_ + jst];

  __syncthreads();   // LDS W ready

  f32x4 xacc0, xacc1;
  // x-part of gates for step t (bias folded in); overlaps the inter-step poll
  auto computeX = [&](int t) {
    xacc0 = f32x4{bias0, bias0, bias0, bias0};
    xacc1 = f32x4{bias1, bias1, bias1, bias1};
    const unsigned short* xrow = xb + ((size_t)t * B_ + mA) * I_ + kOff;
#pragma unroll
    for (int kk = 0; kk < 8; ++kk) {
      bf16x8 a  = *(const bf16x8*)(xrow + kk * 32);
      bf16x8 b0 = *(const bf16x8*)(wlds + ((size_t)(kk) * 64 + lane) * 8);
      bf16x8 b1 = *(const bf16x8*)(wlds + ((size_t)(KSTEPS + kk) * 64 + lane) * 8);
      xacc0 = __builtin_amdgcn_mfma_f32_16x16x32_bf16(a, b0, xacc0, 0, 0, 0);
      xacc1 = __builtin_amdgcn_mfma_f32_16x16x32_bf16(a, b1, xacc1, 0, 0, 0);
    }
  };
  computeX(0);

  for (int t = 0; t < T_; ++t) {
    // ---- per-wave wait: all 512 wave-flags >= t ----
    if (t > 0) {
      const unsigned target = (unsigned)t;
      const unsigned long long* f64 = (const unsigned long long*)flags;
      int guard = 0;
      for (;;) {
        bool ok = true;
#pragma unroll
        for (int q = 0; q < 4; ++q) {
          unsigned long long v = __hip_atomic_load(f64 + (size_t)lane * 4 + q,
                                                   __ATOMIC_RELAXED, __HIP_MEMORY_SCOPE_AGENT);
          ok = ok && ((unsigned)v >= target) && ((unsigned)(v >> 32) >= target);
        }
        if (__all(ok)) break;
        if (++guard > (1 << 20)) break;   // safety: never hard-hang the harness
      }
      asm volatile("" ::: "memory");   // don't hoist h loads above the poll
    }

    // ---- prefetch all 32 h fragments into registers (one addr + imm offsets) ----
    const unsigned short* hprev = (t == 0) ? hbuf : hs + (size_t)(t - 1) * (B_ * H_);
    const unsigned short* hrow = hprev + (size_t)mA * H_ + kOff;
    bf16x8 hf[32];
#pragma unroll
    for (int kk = 0; kk < 32; ++kk)
      hf[kk] = *(const bf16x8*)(hrow + kk * 32);   // plain cached b128 load

    f32x4 acc0 = xacc0, acc1 = xacc1;
#pragma unroll
    for (int kk = 0; kk < 32; ++kk) {
      bf16x8 b0 = *(const bf16x8*)(wlds + ((size_t)(kk + 8) * 64 + lane) * 8);
      bf16x8 b1 = *(const bf16x8*)(wlds + ((size_t)(KSTEPS + kk + 8) * 64 + lane) * 8);
      acc0 = __builtin_amdgcn_mfma_f32_16x16x32_bf16(hf[kk], b0, acc0, 0, 0, 0);
      acc1 = __builtin_amdgcn_mfma_f32_16x16x32_bf16(hf[kk], b1, acc1, 0, 0, 0);
    }

    // gates: acc0 = [i|f], acc1 = [g|o]; f/o live in lane^8
    unsigned short hbits[4];
#pragma unroll
    for (int e = 0; e < 4; ++e) {
      float ip  = acc0[e], gp = acc1[e];
      float fp_ = __shfl_xor(ip, 8);
      float op_ = __shfl_xor(gp, 8);
      float ig = sigm(ip), fg = sigm(fp_), gg = tanh_fast(gp), og = sigm(op_);
      float cn = fg * creg[e] + ig * gg;
      creg[e] = cn;
      hbits[e] = f2bf(og * tanh_fast(cn));
    }

    // store h_t into hs[t]: pair adjacent columns into one dword, write-through
    unsigned short* hsrow = hs + (size_t)t * (B_ * H_);
#pragma unroll
    for (int e = 0; e < 4; ++e) {
      unsigned vpair = (unsigned)hbits[e] | ((unsigned)__shfl_xor((int)hbits[e], 1) << 16);
      if ((lane & 9) == 0) {   // even lanes among owners (lane&8==0)
        unsigned* dst = (unsigned*)(hsrow + (size_t)(mD + e) * H_ + jst);
        __hip_atomic_store(dst, vpair, __ATOMIC_RELAXED, __HIP_MEMORY_SCOPE_AGENT);
      }
    }

    // wave-wide drain of this wave's sc1 stores, then post per-wave flag
    asm volatile("s_waitcnt vmcnt(0)" ::: "memory");
    if (lane == 0)
      __hip_atomic_store(flags + (w << 2) + wave, (unsigned)(t + 1),
                         __ATOMIC_RELAXED, __HIP_MEMORY_SCOPE_AGENT);

    // next step's x-part overlaps the coming poll window
    if (t + 1 < T_) computeX(t + 1);
  }
}

// ---------------- K3: out[t,b,:] = hs[t,b,:] @ W_fc^T + b_fc ----------------
__global__ void k_fc(const unsigned short* __restrict__ hs, const unsigned short* __restrict__ wfcp,
                     const float* __restrict__ bfc, float* __restrict__ out) {
  const int bm = blockIdx.x >> 2, bn = blockIdx.x & 3;
  const int tid = threadIdx.x, wave = tid >> 6, lane = tid & 63;
  const int r    = bm * 64 + wave * 16 + (lane & 15);
  const int kOff = (lane >> 4) * 8;
  const int nb   = bn * 4;   // first 16-wide n-tile index
  f32x4 acc[4];
#pragma unroll
  for (int nt = 0; nt < 4; ++nt) {
    float bv = bfc[(nb + nt) * 16 + (lane & 15)];
    acc[nt] = {bv, bv, bv, bv};
  }
  const unsigned short* arow = hs + (size_t)r * H_ + kOff;
#pragma unroll 2
  for (int kk = 0; kk < 32; ++kk) {
    bf16x8 a = *(const bf16x8*)(arow + kk * 32);
#pragma unroll
    for (int nt = 0; nt < 4; ++nt) {
      bf16x8 b = *(const bf16x8*)(wfcp + ((size_t)(kk * 16 + nb + nt) * 64 + lane) * 8);
      acc[nt] = __builtin_amdgcn_mfma_f32_16x16x32_bf16(a, b, acc[nt], 0, 0, 0);
    }
  }
  const int ro = bm * 64 + wave * 16 + (lane >> 4) * 4;
#pragma unroll
  for (int nt = 0; nt < 4; ++nt)
#pragma unroll
    for (int e = 0; e < 4; ++e)
      out[(size_t)(ro + e) * I_ + (nb + nt) * 16 + (lane & 15)] = acc[nt][e];
}

// ---------------- launcher ----------------
extern "C" void kernel_launch(void* const* d_in, const int* in_sizes, int n_in,
                              void* d_out, int out_size, void* d_ws, size_t ws_size,
                              hipStream_t stream) {
  const float* x   = (const float*)d_in[0];
  const float* h0  = (const float*)d_in[1];
  const float* c0  = (const float*)d_in[2];
  const float* Wih = (const float*)d_in[3];
  const float* Whh = (const float*)d_in[4];
  const float* bih = (const float*)d_in[5];
  const float* bhh = (const float*)d_in[6];
  const float* Wfc = (const float*)d_in[7];
  const float* bfc = (const float*)d_in[8];
  float* out = (float*)d_out;

  char* ws = (char*)d_ws;
  // ws layout (bytes): total ~95.2 MB
  unsigned short* xb    = (unsigned short*)(ws + 0);           // 16,777,216
  unsigned short* hsb   = (unsigned short*)(ws + 16777216);    // 67,108,864
  unsigned short* wpk   = (unsigned short*)(ws + 83886080);    // 10,485,760
  float*          biasp = (float*)        (ws + 94371840);     //     16,384
  unsigned short* wfcp  = (unsigned short*)(ws + 94388224);    //    524,288
  unsigned short* hbuf  = (unsigned short*)(ws + 94912512);    //    262,144
  unsigned int*   flg   = (unsigned int*)  (ws + 95174656);    //      4,096

  k_pack_x  <<<4096, 256, 0, stream>>>(x, xb);
  k_pack_w  <<<2560, 256, 0, stream>>>(Wih, Whh, bih, bhh, wpk, biasp);
  k_pack_wfc<<<128,  256, 0, stream>>>(Wfc, wfcp);
  k_init_h  <<<32,   256, 0, stream>>>(h0, hbuf, flg);
  k_lstm    <<<NWG,  256, 0, stream>>>(xb, wpk, biasp, c0, hbuf, hsb, flg);
  k_fc      <<<2048, 256, 0, stream>>>(hsb, wfcp, bfc, out);
}

// Round 5
// 3890.422 us; speedup vs baseline: 2.1853x; 1.0185x over previous
//
#include <hip/hip_runtime.h>
#include <hip/hip_bf16.h>

// Problem constants
#define B_    64
#define T_    512
#define I_    256
#define H_    1024
#define KTOT  1280          // I_ + H_
#define KSTEPS 40           // KTOT / 32
#define NWG   128           // recurrence workgroups (each owns NJ h-cols)
#define NJ    8             // h-columns per WG -> 32 gate columns
#define WPK_ELEMS (2 * KSTEPS * 64 * 8)   // 40960 bf16 per WG slice (80KB)

typedef __bf16 bf16x8 __attribute__((ext_vector_type(8)));
typedef float  f32x4  __attribute__((ext_vector_type(4)));

__device__ __forceinline__ unsigned short f2bf(float f) {
  unsigned u = __builtin_bit_cast(unsigned, f);
  u += 0x7FFFu + ((u >> 16) & 1u);       // round-to-nearest-even
  return (unsigned short)(u >> 16);
}
__device__ __forceinline__ float sigm(float x) { return 1.0f / (1.0f + __expf(-x)); }
__device__ __forceinline__ float tanh_fast(float x) {
  float ax = fabsf(x);
  float e  = __expf(-2.0f * ax);          // in (0,1], no overflow
  float t  = (1.0f - e) / (1.0f + e);
  return x < 0.0f ? -t : t;
}

// ---------------- K0: x [B,T,I] f32 -> xb [T,B,I] bf16 ----------------
__global__ void k_pack_x(const float* __restrict__ x, unsigned short* __restrict__ xb) {
  int idx = blockIdx.x * blockDim.x + threadIdx.x;   // over B*T*I/8 = 1,048,576
  int ic = idx & 31;             // I/8 = 32
  int t  = (idx >> 5) & 511;     // T = 512
  int b  = idx >> 14;            // B = 64
  const float* src = x + ((size_t)b * T_ + t) * I_ + ic * 8;
  float4 f0 = *(const float4*)src;
  float4 f1 = *(const float4*)(src + 4);
  unsigned short o[8] = {f2bf(f0.x), f2bf(f0.y), f2bf(f0.z), f2bf(f0.w),
                         f2bf(f1.x), f2bf(f1.y), f2bf(f1.z), f2bf(f1.w)};
  *(uint4*)(xb + ((size_t)t * B_ + b) * I_ + ic * 8) = *(uint4*)o;
}

// ---------------- K1a: pack W_ih|W_hh into per-WG B-fragment layout ----------------
__global__ void k_pack_w(const float* __restrict__ Wih, const float* __restrict__ Whh,
                         const float* __restrict__ bih, const float* __restrict__ bhh,
                         unsigned short* __restrict__ wpack, float* __restrict__ biasp) {
  int f = blockIdx.x * blockDim.x + threadIdx.x;     // 128*2*40*64 = 655,360
  int l  = f & 63;
  int q  = f >> 6;
  int kk = q % KSTEPS;
  int q2 = q / KSTEPS;
  int nt = q2 & 1;
  int w  = q2 >> 1;
  int n  = l & 15;
  int g  = nt * 2 + (n >> 3);
  int r  = g * H_ + w * NJ + (n & 7);
  int k0 = kk * 32 + (l >> 4) * 8;
  unsigned short o[8];
#pragma unroll
  for (int e = 0; e < 8; ++e) {
    int k = k0 + e;
    float v = (k < I_) ? Wih[(size_t)r * I_ + k] : Whh[(size_t)r * H_ + (k - I_)];
    o[e] = f2bf(v);
  }
  *(uint4*)(wpack + (size_t)f * 8) = *(uint4*)o;
  if (kk == 0 && (l >> 4) == 0) biasp[w * 32 + nt * 16 + n] = bih[r] + bhh[r];
}

// ---------------- K1b: pack W_fc [I,H] -> fragment layout [kk][nt][lane][e] ----------------
__global__ void k_pack_wfc(const float* __restrict__ Wfc, unsigned short* __restrict__ wfcp) {
  int f = blockIdx.x * blockDim.x + threadIdx.x;     // 32*16*64 = 32768
  int l  = f & 63;
  int nt = (f >> 6) & 15;
  int kk = f >> 10;
  int n  = nt * 16 + (l & 15);
  int k0 = kk * 32 + (l >> 4) * 8;
  unsigned short o[8];
#pragma unroll
  for (int e = 0; e < 8; ++e) o[e] = f2bf(Wfc[(size_t)n * H_ + k0 + e]);
  *(uint4*)(wfcp + (size_t)f * 8) = *(uint4*)o;
}

// ---------------- K1c: h0 -> bf16 hbuf; zero flags ----------------
__global__ void k_init_h(const float* __restrict__ h0, unsigned short* __restrict__ hbuf,
                         unsigned int* __restrict__ flags) {
  int idx = blockIdx.x * blockDim.x + threadIdx.x;   // B*H/8 = 8192
  const float* s = h0 + (size_t)idx * 8;
  unsigned short o[8];
#pragma unroll
  for (int e = 0; e < 8; ++e) o[e] = f2bf(s[e]);
  *(uint4*)(hbuf + (size_t)idx * 8) = *(uint4*)o;
  if (idx < 1024) flags[idx] = 0;
}

// ---------------- K2: persistent LSTM recurrence ----------------
// 128 WGs x 256 threads (4 waves). WG w owns h-cols [w*8, w*8+8). W in LDS.
// Sync per step: each wave drains its sc1 h-stores (vmcnt(0)), lane0 bumps an
// LDS counter; 4th wave posts ONE per-WG flag (agent store). Wave 0 polls all
// 128 flags with coalesced asm sc0/sc1 dwordx2 loads, releases waves via LDS.
// h exchange: sc1 write-through 8B stores into hs[t]; readers: plain cached
// b128 loads, force-prefetched 32-deep (memory-clobber fence) + x(t+1) 8-deep.
__global__ void __launch_bounds__(256, 1) k_lstm(
    const unsigned short* __restrict__ xb, const unsigned short* __restrict__ wpack,
    const float* __restrict__ biasp, const float* __restrict__ c0,
    const unsigned short* __restrict__ hbuf, unsigned short* __restrict__ hs,
    unsigned int* __restrict__ flags) {
  __shared__ unsigned short wlds[WPK_ELEMS];  // 80 KB
  __shared__ unsigned cnt[2];
  __shared__ unsigned go;
  const int w    = blockIdx.x;
  const int tid  = threadIdx.x;
  const int wave = tid >> 6, lane = tid & 63;

  if (tid == 0) { cnt[0] = 0; cnt[1] = 0; go = 0; }
  { // one-time LDS fill of the W slice
    const unsigned short* wp = wpack + (size_t)w * WPK_ELEMS;
    for (int i = tid * 8; i < WPK_ELEMS; i += 256 * 8)
      *(uint4*)(wlds + i) = *(const uint4*)(wp + i);
  }

  const int mA   = wave * 16 + (lane & 15);    // A-fragment row = batch index
  const int kOff = (lane >> 4) * 8;            // A-fragment k offset within 32
  const int mD   = wave * 16 + (lane >> 4) * 4;// D-fragment row base
  const int jst  = w * NJ + (lane & 7);        // owned h-column

  const float bias0 = biasp[w * 32 + (lane & 15)];
  const float bias1 = biasp[w * 32 + 16 + (lane & 15)];
  float creg[4];
#pragma unroll
  for (int e = 0; e < 4; ++e) creg[e] = c0[(size_t)(mD + e) * H_ + jst];

  __syncthreads();   // LDS W + cnt/go ready

  bf16x8 xf[8];      // prefetched x fragments for the NEXT step
  f32x4 xacc0, xacc1;
  auto loadX = [&](int t) {
    const unsigned short* xrow = xb + ((size_t)t * B_ + mA) * I_ + kOff;
#pragma unroll
    for (int kk = 0; kk < 8; ++kk) xf[kk] = *(const bf16x8*)(xrow + kk * 32);
  };
  auto computeX = [&]() {   // consumes xf (registers) + LDS W only
    xacc0 = f32x4{bias0, bias0, bias0, bias0};
    xacc1 = f32x4{bias1, bias1, bias1, bias1};
#pragma unroll
    for (int kk = 0; kk < 8; ++kk) {
      bf16x8 b0 = *(const bf16x8*)(wlds + ((size_t)(kk) * 64 + lane) * 8);
      bf16x8 b1 = *(const bf16x8*)(wlds + ((size_t)(KSTEPS + kk) * 64 + lane) * 8);
      xacc0 = __builtin_amdgcn_mfma_f32_16x16x32_bf16(xf[kk], b0, xacc0, 0, 0, 0);
      xacc1 = __builtin_amdgcn_mfma_f32_16x16x32_bf16(xf[kk], b1, xacc1, 0, 0, 0);
    }
  };
  loadX(0);
  asm volatile("" ::: "memory");
  computeX();

  for (int t = 0; t < T_; ++t) {
    // ---- wait for h_{t-1}: wave0 polls 128 per-WG flags, releases via LDS ----
    if (t > 0) {
      if (wave == 0) {
        const unsigned target = (unsigned)t;
        const unsigned long long* fp = (const unsigned long long*)flags + lane; // 2 flags/lane
        int guard = 0;
        for (;;) {
          unsigned long long v;
          asm volatile("global_load_dwordx2 %0, %1, off sc0 sc1\n\ts_waitcnt vmcnt(0)"
                       : "=&v"(v) : "v"(fp) : "memory");
          if (__all(((unsigned)v >= target) & ((unsigned)(v >> 32) >= target))) break;
          if (++guard > (1 << 20)) break;   // safety: never hard-hang
        }
        __hip_atomic_store(&go, target, __ATOMIC_RELAXED, __HIP_MEMORY_SCOPE_WORKGROUP);
      } else {
        int guard = 0;
        while (__hip_atomic_load(&go, __ATOMIC_RELAXED, __HIP_MEMORY_SCOPE_WORKGROUP)
               < (unsigned)t) {
          if (++guard > (1 << 22)) break;
        }
      }
      asm volatile("" ::: "memory");   // don't hoist h loads above the release
    }

    // ---- force-prefetch: 32 h fragments + 8 x fragments (t+1) ----
    const unsigned short* hprev = (t == 0) ? hbuf : hs + (size_t)(t - 1) * (B_ * H_);
    const unsigned short* hrow = hprev + (size_t)mA * H_ + kOff;
    bf16x8 hf[32];
#pragma unroll
    for (int kk = 0; kk < 32; ++kk)
      hf[kk] = *(const bf16x8*)(hrow + kk * 32);   // plain cached b128 load
    if (t + 1 < T_) loadX(t + 1);
    asm volatile("" ::: "memory");   // loads cannot sink below this point

    f32x4 acc0 = xacc0, acc1 = xacc1;
#pragma unroll
    for (int kk = 0; kk < 32; ++kk) {
      bf16x8 b0 = *(const bf16x8*)(wlds + ((size_t)(kk + 8) * 64 + lane) * 8);
      bf16x8 b1 = *(const bf16x8*)(wlds + ((size_t)(KSTEPS + kk + 8) * 64 + lane) * 8);
      acc0 = __builtin_amdgcn_mfma_f32_16x16x32_bf16(hf[kk], b0, acc0, 0, 0, 0);
      acc1 = __builtin_amdgcn_mfma_f32_16x16x32_bf16(hf[kk], b1, acc1, 0, 0, 0);
    }

    // gates: acc0 = [i|f], acc1 = [g|o]; f/o live in lane^8
    unsigned short hbits[4];
#pragma unroll
    for (int e = 0; e < 4; ++e) {
      float ip  = acc0[e], gp = acc1[e];
      float fp_ = __shfl_xor(ip, 8);
      float op_ = __shfl_xor(gp, 8);
      float ig = sigm(ip), fg = sigm(fp_), gg = tanh_fast(gp), og = sigm(op_);
      float cn = fg * creg[e] + ig * gg;
      creg[e] = cn;
      hbits[e] = f2bf(og * tanh_fast(cn));
    }

    // store h_t: gather 4 columns (lanes l,l^1,l^2,l^3) into one 8B sc1 store
    unsigned short* hsrow = hs + (size_t)t * (B_ * H_);
#pragma unroll
    for (int e = 0; e < 4; ++e) {
      unsigned vpair = (unsigned)hbits[e] | ((unsigned)__shfl_xor((int)hbits[e], 1) << 16);
      unsigned long long vquad =
          (unsigned long long)vpair | ((unsigned long long)__shfl_xor((int)vpair, 2) << 32);
      if ((lane & 11) == 0) {   // lanes 0,4,16,20,32,36,48,52: 8B each
        unsigned long long* dst =
            (unsigned long long*)(hsrow + (size_t)(mD + e) * H_ + jst);
        __hip_atomic_store(dst, vquad, __ATOMIC_RELAXED, __HIP_MEMORY_SCOPE_AGENT);
      }
    }

    // wave-wide drain, then LDS-aggregate; 4th wave posts the per-WG flag
    asm volatile("s_waitcnt vmcnt(0)" ::: "memory");
    if (lane == 0) {
      unsigned old = __hip_atomic_fetch_add(&cnt[t & 1], 1u,
                                            __ATOMIC_RELAXED, __HIP_MEMORY_SCOPE_WORKGROUP);
      if (old == 3) {
        __hip_atomic_store(&cnt[t & 1], 0u, __ATOMIC_RELAXED, __HIP_MEMORY_SCOPE_WORKGROUP);
        __hip_atomic_store(flags + w, (unsigned)(t + 1),
                           __ATOMIC_RELAXED, __HIP_MEMORY_SCOPE_AGENT);
      }
    }

    // next step's x-part (registers + LDS only) overlaps the coming poll
    if (t + 1 < T_) computeX();
  }
}

// ---------------- K3: out[t,b,:] = hs[t,b,:] @ W_fc^T + b_fc ----------------
__global__ void k_fc(const unsigned short* __restrict__ hs, const unsigned short* __restrict__ wfcp,
                     const float* __restrict__ bfc, float* __restrict__ out) {
  const int bm = blockIdx.x >> 2, bn = blockIdx.x & 3;
  const int tid = threadIdx.x, wave = tid >> 6, lane = tid & 63;
  const int r    = bm * 64 + wave * 16 + (lane & 15);
  const int kOff = (lane >> 4) * 8;
  const int nb   = bn * 4;   // first 16-wide n-tile index
  f32x4 acc[4];
#pragma unroll
  for (int nt = 0; nt < 4; ++nt) {
    float bv = bfc[(nb + nt) * 16 + (lane & 15)];
    acc[nt] = {bv, bv, bv, bv};
  }
  const unsigned short* arow = hs + (size_t)r * H_ + kOff;
#pragma unroll 2
  for (int kk = 0; kk < 32; ++kk) {
    bf16x8 a = *(const bf16x8*)(arow + kk * 32);
#pragma unroll
    for (int nt = 0; nt < 4; ++nt) {
      bf16x8 b = *(const bf16x8*)(wfcp + ((size_t)(kk * 16 + nb + nt) * 64 + lane) * 8);
      acc[nt] = __builtin_amdgcn_mfma_f32_16x16x32_bf16(a, b, acc[nt], 0, 0, 0);
    }
  }
  const int ro = bm * 64 + wave * 16 + (lane >> 4) * 4;
#pragma unroll
  for (int nt = 0; nt < 4; ++nt)
#pragma unroll
    for (int e = 0; e < 4; ++e)
      out[(size_t)(ro + e) * I_ + (nb + nt) * 16 + (lane & 15)] = acc[nt][e];
}

// ---------------- launcher ----------------
extern "C" void kernel_launch(void* const* d_in, const int* in_sizes, int n_in,
                              void* d_out, int out_size, void* d_ws, size_t ws_size,
                              hipStream_t stream) {
  const float* x   = (const float*)d_in[0];
  const float* h0  = (const float*)d_in[1];
  const float* c0  = (const float*)d_in[2];
  const float* Wih = (const float*)d_in[3];
  const float* Whh = (const float*)d_in[4];
  const float* bih = (const float*)d_in[5];
  const float* bhh = (const float*)d_in[6];
  const float* Wfc = (const float*)d_in[7];
  const float* bfc = (const float*)d_in[8];
  float* out = (float*)d_out;

  char* ws = (char*)d_ws;
  // ws layout (bytes): total ~95.2 MB
  unsigned short* xb    = (unsigned short*)(ws + 0);           // 16,777,216
  unsigned short* hsb   = (unsigned short*)(ws + 16777216);    // 67,108,864
  unsigned short* wpk   = (unsigned short*)(ws + 83886080);    // 10,485,760
  float*          biasp = (float*)        (ws + 94371840);     //     16,384
  unsigned short* wfcp  = (unsigned short*)(ws + 94388224);    //    524,288
  unsigned short* hbuf  = (unsigned short*)(ws + 94912512);    //    262,144
  unsigned int*   flg   = (unsigned int*)  (ws + 95174656);    //      4,096

  k_pack_x  <<<4096, 256, 0, stream>>>(x, xb);
  k_pack_w  <<<2560, 256, 0, stream>>>(Wih, Whh, bih, bhh, wpk, biasp);
  k_pack_wfc<<<128,  256, 0, stream>>>(Wfc, wfcp);
  k_init_h  <<<32,   256, 0, stream>>>(h0, hbuf, flg);
  k_lstm    <<<NWG,  256, 0, stream>>>(xb, wpk, biasp, c0, hbuf, hsb, flg);
  k_fc      <<<2048, 256, 0, stream>>>(hsb, wfcp, bfc, out);
}